// Round 6
// baseline (241.384 us; speedup 1.0000x reference)
//
#include <hip/hip_runtime.h>
#include <hip/hip_fp16.h>

// Problem constants (fixed by the reference): B=2, T=2048, E=1024, H=16, d=64
#define B_NUM  2
#define T_DIM  2048
#define E_DIM  1024
#define H_NUM  16
#define D_HEAD 64
#define BH_NUM (B_NUM * H_NUM)
#define NT     (T_DIM / 64)      // 32 s-tiles
#define QT2    (T_DIM / 128)     // 16 q-tiles of 128 rows

using half8  = __attribute__((ext_vector_type(8))) _Float16;
using half4v = __attribute__((ext_vector_type(4))) _Float16;
using f32x4  = __attribute__((ext_vector_type(4))) float;

#define AS1 __attribute__((address_space(1)))
#define AS3 __attribute__((address_space(3)))

// 1/sqrt(64) * log2(e): MFMA yields S*log2e, so v_exp_f32 (2^x) == exp(S)
#define QSCALE 0.18033688011112042f

// Mid-tile barrier: retire the previous cooperative stage (own-wave count N =
// number of VMEM ops issued AFTER the target stage), then sync so all waves'
// stages are visible. sched_barrier stops the compiler hoisting the LDS
// reads above the wait (rule #18).
#define BAR_VM(N)                                                       \
    do {                                                                \
        asm volatile("s_waitcnt vmcnt(" #N ")" ::: "memory");           \
        __builtin_amdgcn_s_barrier();                                   \
        __builtin_amdgcn_sched_barrier(0);                              \
    } while (0)

// End-of-tile barrier: all waves finished READING the current LDS buffer, so
// the next iteration may issue stages that overwrite it. No counter drain.
__device__ __forceinline__ void bar_plain() {
    __builtin_amdgcn_s_barrier();
    __builtin_amdgcn_sched_barrier(0);
}

// ---------------------------------------------------------------------------
// cast f32 -> f16 (vectorized, grid-stride)
// ---------------------------------------------------------------------------
__global__ void cast_f16_kernel(const float* __restrict__ in,
                                _Float16* __restrict__ out, int n4) {
    int stride = gridDim.x * blockDim.x;
    for (int i = blockIdx.x * blockDim.x + threadIdx.x; i < n4; i += stride) {
        float4 v = reinterpret_cast<const float4*>(in)[i];
        half4v h;
        h[0] = (_Float16)v.x; h[1] = (_Float16)v.y;
        h[2] = (_Float16)v.z; h[3] = (_Float16)v.w;
        reinterpret_cast<half4v*>(out)[i] = h;
    }
}

// ---------------------------------------------------------------------------
// V [B,T,E] f32  ->  Vt [BH, D_HEAD, T] f16   (per-head transpose, LDS tiled)
// ---------------------------------------------------------------------------
__global__ void transpose_v_kernel(const float* __restrict__ V,
                                   _Float16* __restrict__ Vt) {
    __shared__ float tile[64][65];
    int s0 = blockIdx.x * 64;
    int bh = blockIdx.y;
    int b = bh >> 4, h = bh & 15;
    int t = threadIdx.x;

    int row = t >> 2;
    int c0  = (t & 3) * 16;
    const float* src = V + ((size_t)(b * T_DIM + s0 + row)) * E_DIM + h * D_HEAD + c0;
#pragma unroll
    for (int j = 0; j < 16; j += 4) {
        float4 v = *reinterpret_cast<const float4*>(src + j);
        tile[row][c0 + j + 0] = v.x;
        tile[row][c0 + j + 1] = v.y;
        tile[row][c0 + j + 2] = v.z;
        tile[row][c0 + j + 3] = v.w;
    }
    __syncthreads();

    int d  = t >> 2;
    int sc = (t & 3) * 16;
    half8 h0, h1;
#pragma unroll
    for (int j = 0; j < 8; ++j) {
        h0[j] = (_Float16)tile[sc + j][d];
        h1[j] = (_Float16)tile[sc + 8 + j][d];
    }
    _Float16* dst = Vt + ((size_t)(bh * D_HEAD + d)) * T_DIM + s0 + sc;
    *reinterpret_cast<half8*>(dst)     = h0;
    *reinterpret_cast<half8*>(dst + 8) = h1;
}

// ---------------------------------------------------------------------------
// 64x64 f16 LDS tile, 16B-chunk XOR swizzle (chunk' = chunk ^ (row&7)),
// staged via global_load_lds (width 16) with inverse-swizzled SOURCE
// addresses (linear LDS dest; lane = r0*8 + csw -> lane*16 linear).
// 8-wave version: wave w stages rows w*8..w*8+7 with ONE op.
// ---------------------------------------------------------------------------
__device__ __forceinline__ void stage8(const _Float16* __restrict__ g,
                                       size_t stride, _Float16* lds,
                                       int w, int lane) {
    int r0 = lane >> 3;
    int c  = (lane & 7) ^ r0;
    const _Float16* src = g + (size_t)(w * 8 + r0) * stride + c * 8;
    _Float16* dst = lds + w * 512;   // wave-uniform base
    __builtin_amdgcn_global_load_lds((const AS1 void*)src, (AS3 void*)dst,
                                     16, 0, 0);
}

// 4-wave version for proj (wave w covers rows 8*(w+4j), j=0,1)
__device__ __forceinline__ void stage_gl(const _Float16* __restrict__ g,
                                         size_t stride, _Float16* lds,
                                         int w, int lane) {
    int r0 = lane >> 3;
    int c  = (lane & 7) ^ r0;
#pragma unroll
    for (int j = 0; j < 2; ++j) {
        int r = (w + 4 * j) * 8 + r0;
        const _Float16* src = g + (size_t)r * stride + c * 8;
        _Float16* dst = lds + (w + 4 * j) * 512;
        __builtin_amdgcn_global_load_lds((const AS1 void*)src, (AS3 void*)dst,
                                         16, 0, 0);
    }
}

__device__ __forceinline__ half8 read_frag64(const _Float16* lds, int row, int chunk) {
    int csw = chunk ^ (row & 7);
    return *reinterpret_cast<const half8*>(lds + row * 64 + csw * 8);
}

// ---------------------------------------------------------------------------
// Fused attention: 8 waves = 128 q rows per block (halves K/V re-stage
// traffic vs 64-row blocks). LDS-staged K/V, two barriers per tile
// (BAR_VM: stage visible, stores stay in flight; bar_plain: buffer reuse),
// nt P-stores, XCD swizzle (4 bh per XCD, 2 MB < 4 MiB per-XCD L2).
// Operand-swapped QK^T: acc = mfma(A=K_frag, B=Q_frag) ->
//   lane (l15,lg) holds S[q=l15][s = ct*16 + lg*4 + r] (4 consecutive s).
// ---------------------------------------------------------------------------
__global__ __launch_bounds__(512) void attn_kernel(
        const float* __restrict__ Q, const _Float16* __restrict__ Kh,
        const _Float16* __restrict__ Vt, float* __restrict__ attn_out,
        _Float16* __restrict__ head_h) {
    __shared__ __align__(16) _Float16 kbuf[2][64 * 64];
    __shared__ __align__(16) _Float16 vbuf[2][64 * 64];
    __shared__ __align__(16) _Float16 pbuf[8][16 * 64];

    int tid  = threadIdx.x;
    int wq   = tid >> 6;       // wave 0..7
    int lane = tid & 63;
    int l15  = lane & 15;
    int lg   = lane >> 4;

    // XCD swizzle: 512 blocks; xcd = flat&7 hosts bh {4*xcd..4*xcd+3}.
    int flat = blockIdx.x;
    int i    = flat >> 3;             // 0..63
    int bh   = (flat & 7) * 4 + (i >> 4);
    int qt   = i & 15;
    int q0   = qt * 128;
    int b = bh >> 4, h = bh & 15;

    // Q B-fragment: B[k=(lg+4ks)*8+i][col=q=l15]; pre-scaled by log2e/sqrt(d)
    const float* qsrc = Q + ((size_t)(b * T_DIM + q0 + wq * 16 + l15)) * E_DIM + h * D_HEAD;
    half8 qfrag[2];
#pragma unroll
    for (int ks = 0; ks < 2; ++ks) {
        float4 a0 = *reinterpret_cast<const float4*>(qsrc + (lg + 4 * ks) * 8);
        float4 a1 = *reinterpret_cast<const float4*>(qsrc + (lg + 4 * ks) * 8 + 4);
        qfrag[ks][0] = (_Float16)(a0.x * QSCALE); qfrag[ks][1] = (_Float16)(a0.y * QSCALE);
        qfrag[ks][2] = (_Float16)(a0.z * QSCALE); qfrag[ks][3] = (_Float16)(a0.w * QSCALE);
        qfrag[ks][4] = (_Float16)(a1.x * QSCALE); qfrag[ks][5] = (_Float16)(a1.y * QSCALE);
        qfrag[ks][6] = (_Float16)(a1.z * QSCALE); qfrag[ks][7] = (_Float16)(a1.w * QSCALE);
    }

    const _Float16* kg = Kh + ((size_t)b * T_DIM) * E_DIM + h * D_HEAD;
    const _Float16* vg = Vt + (size_t)bh * D_HEAD * T_DIM;

#define P1TILE(KB)                                                             \
    {                                                                          \
        f32x4 acc[4];                                                          \
        _Pragma("unroll")                                                      \
        for (int ct = 0; ct < 4; ++ct) acc[ct] = (f32x4){0.f, 0.f, 0.f, 0.f};  \
        _Pragma("unroll")                                                      \
        for (int ks = 0; ks < 2; ++ks)                                         \
            _Pragma("unroll")                                                  \
            for (int ct = 0; ct < 4; ++ct) {                                   \
                half8 kf = read_frag64((KB), ct * 16 + l15, lg + 4 * ks);      \
                acc[ct] = __builtin_amdgcn_mfma_f32_16x16x32_f16(              \
                    kf, qfrag[ks], acc[ct], 0, 0, 0);                          \
            }                                                                  \
        _Pragma("unroll")                                                      \
        for (int ct = 0; ct < 4; ++ct)                                         \
            _Pragma("unroll")                                                  \
            for (int r = 0; r < 4; ++r)                                        \
                lsum += __builtin_amdgcn_exp2f(acc[ct][r]);                    \
    }

    // ---------------- pass 1: row sums ----------------
    // Per-wave VMEM FIFO: stage(t)=1 op. After stage(t): stage(t+1)=1 ->
    // BAR_VM(1); final tile: BAR_VM(0).
    float lsum = 0.0f;
    int cur = 0;
    stage8(kg, E_DIM, kbuf[0], wq, lane);
    for (int t = 0; t < NT - 1; ++t) {
        stage8(kg + (size_t)(t + 1) * 64 * E_DIM, E_DIM, kbuf[cur ^ 1], wq, lane);
        BAR_VM(1);                     // stage(t) staged & visible
        P1TILE(kbuf[cur]);
        bar_plain();                   // kbuf[cur] reads done; next overwrite ok
        cur ^= 1;
    }
    BAR_VM(0);
    P1TILE(kbuf[cur]);

    // reduce across the 4 lg replicas of each q row
    lsum += __shfl_xor(lsum, 16);
    lsum += __shfl_xor(lsum, 32);
    float rl = 1.0f / lsum;

    f32x4 oacc[4];
#pragma unroll
    for (int cd = 0; cd < 4; ++cd) oacc[cd] = (f32x4){0.f, 0.f, 0.f, 0.f};

    float* ab = attn_out + (size_t)bh * T_DIM * T_DIM;
    _Float16* pw = pbuf[wq];
    int myq = q0 + wq * 16 + l15;

    // boundary: all waves done with pass-1 kbuf reads before pass-2 staging
    bar_plain();

    // ---------------- pass 2: P write + PV ----------------
    // Per-wave VMEM FIFO per tile: stage(t)=2 (K+V), stores(t)=4.
    // After stage(t): t==0 -> stage(1)=2 -> BAR_VM(2); 1<=t<=NT-2 ->
    // stores(t-1)+stage(t+1)=6 -> BAR_VM(6); t==NT-1 -> stores(NT-2)=4.
    cur = 0;
    stage8(kg, E_DIM, kbuf[0], wq, lane);
    stage8(vg, T_DIM, vbuf[0], wq, lane);
    for (int t = 0; t < NT; ++t) {
        if (t < NT - 1) {
            stage8(kg + (size_t)(t + 1) * 64 * E_DIM, E_DIM, kbuf[cur ^ 1], wq, lane);
            stage8(vg + (t + 1) * 64, T_DIM, vbuf[cur ^ 1], wq, lane);
        }
        if (t == 0)           BAR_VM(2);
        else if (t < NT - 1)  BAR_VM(6);   // P-stores ride ~1.5 tiles in flight
        else                  BAR_VM(4);
        const _Float16* kb = kbuf[cur];
        const _Float16* vb = vbuf[cur];

        f32x4 acc[4];
#pragma unroll
        for (int ct = 0; ct < 4; ++ct) acc[ct] = (f32x4){0.f, 0.f, 0.f, 0.f};
#pragma unroll
        for (int ks = 0; ks < 2; ++ks)
#pragma unroll
            for (int ct = 0; ct < 4; ++ct) {
                half8 kf = read_frag64(kb, ct * 16 + l15, lg + 4 * ks);
                acc[ct] = __builtin_amdgcn_mfma_f32_16x16x32_f16(kf, qfrag[ks], acc[ct], 0, 0, 0);
            }

        // P: one nt dwordx4 global store + one b64 pbuf write per ct
        float* abrow = ab + (size_t)myq * T_DIM + t * 64 + lg * 4;
#pragma unroll
        for (int ct = 0; ct < 4; ++ct) {
            f32x4 p;
            p[0] = __builtin_amdgcn_exp2f(acc[ct][0]) * rl;
            p[1] = __builtin_amdgcn_exp2f(acc[ct][1]) * rl;
            p[2] = __builtin_amdgcn_exp2f(acc[ct][2]) * rl;
            p[3] = __builtin_amdgcn_exp2f(acc[ct][3]) * rl;
            __builtin_nontemporal_store(p, reinterpret_cast<f32x4*>(abrow + ct * 16));
            half4v ph;
            ph[0] = (_Float16)p[0]; ph[1] = (_Float16)p[1];
            ph[2] = (_Float16)p[2]; ph[3] = (_Float16)p[3];
            int cc = (ct * 4 + lg) ^ l15;          // 4-bit XOR: bank-balanced
            *reinterpret_cast<half4v*>(pw + l15 * 64 + cc * 4) = ph;
        }

        // PV: A = P[q=l15][s], B = V[s][d] (vbuf rows are d from Vt)
#pragma unroll
        for (int ks = 0; ks < 2; ++ks) {
            int c0 = 2 * (lg + 4 * ks);
            half4v lo = *reinterpret_cast<const half4v*>(pw + l15 * 64 + ((c0)     ^ l15) * 4);
            half4v hi = *reinterpret_cast<const half4v*>(pw + l15 * 64 + ((c0 + 1) ^ l15) * 4);
            half8 pa;
            pa[0] = lo[0]; pa[1] = lo[1]; pa[2] = lo[2]; pa[3] = lo[3];
            pa[4] = hi[0]; pa[5] = hi[1]; pa[6] = hi[2]; pa[7] = hi[3];
#pragma unroll
            for (int cd = 0; cd < 4; ++cd) {
                half8 vf = read_frag64(vb, cd * 16 + l15, lg + 4 * ks);
                oacc[cd] = __builtin_amdgcn_mfma_f32_16x16x32_f16(pa, vf, oacc[cd], 0, 0, 0);
            }
        }
        bar_plain();                   // buf[cur] reads done; next overwrite ok
        cur ^= 1;
    }

    // head (f16) -> workspace [B*T][E]; O[q=lg*4+r][d=cd*16+l15]
    _Float16* hw = head_h + ((size_t)(b * T_DIM + q0 + wq * 16)) * E_DIM + h * D_HEAD;
#pragma unroll
    for (int cd = 0; cd < 4; ++cd)
#pragma unroll
        for (int r = 0; r < 4; ++r) {
            int qm = lg * 4 + r;
            hw[(size_t)qm * E_DIM + cd * 16 + l15] = (_Float16)oacc[cd][r];
        }
#undef P1TILE
}

// ---------------------------------------------------------------------------
// outputs[m][n] = sum_k head[m][k]*W[n][k]  (M=4096,N=1024,K=1024)
// Operand-swapped: acc = mfma(A=W_frag, B=head_frag) -> nt dwordx4 C stores.
// ---------------------------------------------------------------------------
__global__ __launch_bounds__(256) void proj_kernel(
        const _Float16* __restrict__ A, const _Float16* __restrict__ Wh,
        float* __restrict__ out) {
    __shared__ __align__(16) _Float16 abuf[2][64 * 64];
    __shared__ __align__(16) _Float16 bbuf[2][64 * 64];

    int tid  = threadIdx.x;
    int wq   = tid >> 6;
    int lane = tid & 63;
    int l15  = lane & 15;
    int lg   = lane >> 4;

    int m0 = blockIdx.x * 64;
    int n0 = blockIdx.y * 64;

    f32x4 acc[4];
#pragma unroll
    for (int ct = 0; ct < 4; ++ct) acc[ct] = (f32x4){0.f, 0.f, 0.f, 0.f};

    int cur = 0;
    stage_gl(A  + (size_t)m0 * E_DIM, E_DIM, abuf[0], wq, lane);
    stage_gl(Wh + (size_t)n0 * E_DIM, E_DIM, bbuf[0], wq, lane);
    for (int t = 0; t < E_DIM / 64; ++t) {
        if (t + 1 < E_DIM / 64) {
            stage_gl(A  + (size_t)m0 * E_DIM + (t + 1) * 64, E_DIM, abuf[cur ^ 1], wq, lane);
            stage_gl(Wh + (size_t)n0 * E_DIM + (t + 1) * 64, E_DIM, bbuf[cur ^ 1], wq, lane);
            BAR_VM(4);                 // 4 ops issued after stage(t)
        } else {
            BAR_VM(0);
        }
#pragma unroll
        for (int ks = 0; ks < 2; ++ks) {
            half8 hf = read_frag64(abuf[cur], wq * 16 + l15, lg + 4 * ks);
#pragma unroll
            for (int ct = 0; ct < 4; ++ct) {
                half8 wf = read_frag64(bbuf[cur], ct * 16 + l15, lg + 4 * ks);
                acc[ct] = __builtin_amdgcn_mfma_f32_16x16x32_f16(wf, hf, acc[ct], 0, 0, 0);
            }
        }
        bar_plain();                   // buf[cur] reads done before overwrite
        cur ^= 1;
    }

    float* orow = out + (size_t)(m0 + wq * 16 + l15) * E_DIM + n0 + lg * 4;
#pragma unroll
    for (int ct = 0; ct < 4; ++ct) {
        f32x4 o;
        o[0] = acc[ct][0]; o[1] = acc[ct][1]; o[2] = acc[ct][2]; o[3] = acc[ct][3];
        __builtin_nontemporal_store(o, reinterpret_cast<f32x4*>(orow + ct * 16));
    }
}

// ---------------------------------------------------------------------------
extern "C" void kernel_launch(void* const* d_in, const int* in_sizes, int n_in,
                              void* d_out, int out_size, void* d_ws, size_t ws_size,
                              hipStream_t stream) {
    const float* q = (const float*)d_in[0];
    const float* k = (const float*)d_in[1];
    const float* v = (const float*)d_in[2];
    const float* w = (const float*)d_in[3];

    float* outs = (float*)d_out;
    float* attn = outs + (size_t)B_NUM * T_DIM * E_DIM;   // [32,2048,2048]

    char* ws = (char*)d_ws;
    _Float16* Kh = (_Float16*)(ws);
    _Float16* Vt = (_Float16*)(ws + (size_t)(8  << 20));
    _Float16* Wh = (_Float16*)(ws + (size_t)(16 << 20));
    _Float16* Hh = (_Float16*)(ws + (size_t)(18 << 20));

    int nqkv4 = B_NUM * T_DIM * E_DIM / 4;
    int nw4   = E_DIM * E_DIM / 4;

    cast_f16_kernel<<<1024, 256, 0, stream>>>(k, Kh, nqkv4);
    cast_f16_kernel<<<512, 256, 0, stream>>>(w, Wh, nw4);
    transpose_v_kernel<<<dim3(T_DIM / 64, BH_NUM), 256, 0, stream>>>(v, Vt);
    attn_kernel<<<QT2 * BH_NUM, 512, 0, stream>>>(q, Kh, Vt, attn, Hh);
    proj_kernel<<<dim3((B_NUM * T_DIM) / 64, E_DIM / 64), 256, 0, stream>>>(Hh, Wh, outs);
}

// Round 7
// 223.595 us; speedup vs baseline: 1.0796x; 1.0796x over previous
//
#include <hip/hip_runtime.h>
#include <hip/hip_fp16.h>

// Problem constants (fixed by the reference): B=2, T=2048, E=1024, H=16, d=64
#define B_NUM  2
#define T_DIM  2048
#define E_DIM  1024
#define H_NUM  16
#define D_HEAD 64
#define BH_NUM (B_NUM * H_NUM)
#define NT     (T_DIM / 64)

using half8  = __attribute__((ext_vector_type(8))) _Float16;
using half4v = __attribute__((ext_vector_type(4))) _Float16;
using f32x4  = __attribute__((ext_vector_type(4))) float;

#define AS1 __attribute__((address_space(1)))
#define AS3 __attribute__((address_space(3)))

// 1/sqrt(64) * log2(e): MFMA yields S*log2e, so v_exp_f32 (2^x) == exp(S)
#define QSCALE 0.18033688011112042f

// Mid-tile barrier: retire the previous cooperative stage (own-wave count N =
// number of VMEM ops issued AFTER the target stage), then sync so all waves'
// stages are visible. sched_barrier stops the compiler hoisting the LDS
// reads above the wait (rule #18).
#define BAR_VM(N)                                                       \
    do {                                                                \
        asm volatile("s_waitcnt vmcnt(" #N ")" ::: "memory");           \
        __builtin_amdgcn_s_barrier();                                   \
        __builtin_amdgcn_sched_barrier(0);                              \
    } while (0)

// End-of-tile barrier: all waves finished READING the current LDS buffer, so
// the next iteration may issue stages that overwrite it. No counter drain.
__device__ __forceinline__ void bar_plain() {
    __builtin_amdgcn_s_barrier();
    __builtin_amdgcn_sched_barrier(0);
}

// ---------------------------------------------------------------------------
// cast f32 -> f16 (vectorized, grid-stride)
// ---------------------------------------------------------------------------
__global__ void cast_f16_kernel(const float* __restrict__ in,
                                _Float16* __restrict__ out, int n4) {
    int stride = gridDim.x * blockDim.x;
    for (int i = blockIdx.x * blockDim.x + threadIdx.x; i < n4; i += stride) {
        float4 v = reinterpret_cast<const float4*>(in)[i];
        half4v h;
        h[0] = (_Float16)v.x; h[1] = (_Float16)v.y;
        h[2] = (_Float16)v.z; h[3] = (_Float16)v.w;
        reinterpret_cast<half4v*>(out)[i] = h;
    }
}

// ---------------------------------------------------------------------------
// V [B,T,E] f32  ->  Vt [BH, D_HEAD, T] f16   (per-head transpose, LDS tiled)
// ---------------------------------------------------------------------------
__global__ void transpose_v_kernel(const float* __restrict__ V,
                                   _Float16* __restrict__ Vt) {
    __shared__ float tile[64][65];
    int s0 = blockIdx.x * 64;
    int bh = blockIdx.y;
    int b = bh >> 4, h = bh & 15;
    int t = threadIdx.x;

    int row = t >> 2;
    int c0  = (t & 3) * 16;
    const float* src = V + ((size_t)(b * T_DIM + s0 + row)) * E_DIM + h * D_HEAD + c0;
#pragma unroll
    for (int j = 0; j < 16; j += 4) {
        float4 v = *reinterpret_cast<const float4*>(src + j);
        tile[row][c0 + j + 0] = v.x;
        tile[row][c0 + j + 1] = v.y;
        tile[row][c0 + j + 2] = v.z;
        tile[row][c0 + j + 3] = v.w;
    }
    __syncthreads();

    int d  = t >> 2;
    int sc = (t & 3) * 16;
    half8 h0, h1;
#pragma unroll
    for (int j = 0; j < 8; ++j) {
        h0[j] = (_Float16)tile[sc + j][d];
        h1[j] = (_Float16)tile[sc + 8 + j][d];
    }
    _Float16* dst = Vt + ((size_t)(bh * D_HEAD + d)) * T_DIM + s0 + sc;
    *reinterpret_cast<half8*>(dst)     = h0;
    *reinterpret_cast<half8*>(dst + 8) = h1;
}

// ---------------------------------------------------------------------------
// 64x64 f16 LDS tile, 16B-chunk XOR swizzle (chunk' = chunk ^ (row&7)),
// staged via global_load_lds (width 16) with inverse-swizzled SOURCE
// addresses (linear LDS dest). 2 VMEM ops per wave per tile (4 waves).
// ---------------------------------------------------------------------------
__device__ __forceinline__ void stage_gl(const _Float16* __restrict__ g,
                                         size_t stride, _Float16* lds,
                                         int w, int lane) {
    int r0 = lane >> 3;
    int c  = (lane & 7) ^ r0;
#pragma unroll
    for (int j = 0; j < 2; ++j) {
        int r = (w + 4 * j) * 8 + r0;
        const _Float16* src = g + (size_t)r * stride + c * 8;
        _Float16* dst = lds + (w + 4 * j) * 512;   // wave-uniform base
        __builtin_amdgcn_global_load_lds((const AS1 void*)src, (AS3 void*)dst,
                                         16, 0, 0);
    }
}

__device__ __forceinline__ half8 read_frag64(const _Float16* lds, int row, int chunk) {
    int csw = chunk ^ (row & 7);
    return *reinterpret_cast<const half8*>(lds + row * 64 + csw * 8);
}

// ---------------------------------------------------------------------------
// Fused attention (round-5 structure: 4 waves / 64 q-rows / 1024 blocks).
// LDS-staged K/V, two barriers per tile (BAR_VM: stage visible, stores stay
// in flight; bar_plain: buffer reuse). PLAIN cacheable P-stores: L2
// write-combines the 4x64B row segments into full lines (nt bypassed this).
// XCD swizzle: 4 bh per XCD.
// Operand-swapped QK^T: acc = mfma(A=K_frag, B=Q_frag) ->
//   lane (l15,lg) holds S[q=l15][s = ct*16 + lg*4 + r] (4 consecutive s).
// ---------------------------------------------------------------------------
__global__ __launch_bounds__(256) void attn_kernel(
        const float* __restrict__ Q, const _Float16* __restrict__ Kh,
        const _Float16* __restrict__ Vt, float* __restrict__ attn_out,
        _Float16* __restrict__ head_h) {
    __shared__ __align__(16) _Float16 kbuf[2][64 * 64];
    __shared__ __align__(16) _Float16 vbuf[2][64 * 64];
    __shared__ __align__(16) _Float16 pbuf[4][16 * 64];

    int tid  = threadIdx.x;
    int wq   = tid >> 6;
    int lane = tid & 63;
    int l15  = lane & 15;
    int lg   = lane >> 4;

    // XCD swizzle: xcd = flat&7 hosts bh {4*xcd .. 4*xcd+3}; qt = (flat>>3)&31
    int flat = blockIdx.x;
    int bh   = (flat & 7) * 4 + (flat >> 8);
    int qt   = (flat >> 3) & 31;
    int q0   = qt * 64;
    int b = bh >> 4, h = bh & 15;

    // Q B-fragment: B[k=(lg+4ks)*8+i][col=q=l15]; pre-scaled by log2e/sqrt(d)
    const float* qsrc = Q + ((size_t)(b * T_DIM + q0 + wq * 16 + l15)) * E_DIM + h * D_HEAD;
    half8 qfrag[2];
#pragma unroll
    for (int ks = 0; ks < 2; ++ks) {
        float4 a0 = *reinterpret_cast<const float4*>(qsrc + (lg + 4 * ks) * 8);
        float4 a1 = *reinterpret_cast<const float4*>(qsrc + (lg + 4 * ks) * 8 + 4);
        qfrag[ks][0] = (_Float16)(a0.x * QSCALE); qfrag[ks][1] = (_Float16)(a0.y * QSCALE);
        qfrag[ks][2] = (_Float16)(a0.z * QSCALE); qfrag[ks][3] = (_Float16)(a0.w * QSCALE);
        qfrag[ks][4] = (_Float16)(a1.x * QSCALE); qfrag[ks][5] = (_Float16)(a1.y * QSCALE);
        qfrag[ks][6] = (_Float16)(a1.z * QSCALE); qfrag[ks][7] = (_Float16)(a1.w * QSCALE);
    }

    const _Float16* kg = Kh + ((size_t)b * T_DIM) * E_DIM + h * D_HEAD;
    const _Float16* vg = Vt + (size_t)bh * D_HEAD * T_DIM;

#define P1TILE(KB)                                                             \
    {                                                                          \
        f32x4 acc[4];                                                          \
        _Pragma("unroll")                                                      \
        for (int ct = 0; ct < 4; ++ct) acc[ct] = (f32x4){0.f, 0.f, 0.f, 0.f};  \
        _Pragma("unroll")                                                      \
        for (int ks = 0; ks < 2; ++ks)                                         \
            _Pragma("unroll")                                                  \
            for (int ct = 0; ct < 4; ++ct) {                                   \
                half8 kf = read_frag64((KB), ct * 16 + l15, lg + 4 * ks);      \
                acc[ct] = __builtin_amdgcn_mfma_f32_16x16x32_f16(              \
                    kf, qfrag[ks], acc[ct], 0, 0, 0);                          \
            }                                                                  \
        _Pragma("unroll")                                                      \
        for (int ct = 0; ct < 4; ++ct)                                         \
            _Pragma("unroll")                                                  \
            for (int r = 0; r < 4; ++r)                                        \
                lsum += __builtin_amdgcn_exp2f(acc[ct][r]);                    \
    }

    // ---------------- pass 1: row sums ----------------
    // Per-wave VMEM FIFO: stage(t)=2 ops. Ops issued after stage(t): 2
    // (stage(t+1)) -> BAR_VM(2); final tile: none -> BAR_VM(0).
    float lsum = 0.0f;
    int cur = 0;
    stage_gl(kg, E_DIM, kbuf[0], wq, lane);
    for (int t = 0; t < NT - 1; ++t) {
        stage_gl(kg + (size_t)(t + 1) * 64 * E_DIM, E_DIM, kbuf[cur ^ 1], wq, lane);
        BAR_VM(2);                     // stage(t) staged & visible
        P1TILE(kbuf[cur]);
        bar_plain();                   // kbuf[cur] reads done; next overwrite ok
        cur ^= 1;
    }
    BAR_VM(0);
    P1TILE(kbuf[cur]);

    // reduce across the 4 lg replicas of each q row
    lsum += __shfl_xor(lsum, 16);
    lsum += __shfl_xor(lsum, 32);
    float rl = 1.0f / lsum;

    f32x4 oacc[4];
#pragma unroll
    for (int cd = 0; cd < 4; ++cd) oacc[cd] = (f32x4){0.f, 0.f, 0.f, 0.f};

    float* ab = attn_out + (size_t)bh * T_DIM * T_DIM;
    _Float16* pw = pbuf[wq];
    int myq = q0 + wq * 16 + l15;

    // boundary: all waves done with pass-1 kbuf reads before pass-2 staging
    bar_plain();

    // ---------------- pass 2: P write + PV ----------------
    // Per-wave VMEM FIFO per tile: stage(t)=4 (K2+V2), stores(t)=4.
    // Ops issued after stage(t): t==0 -> stage(1)=4; 1<=t<=NT-2 ->
    // stores(t-1)+stage(t+1)=8; t==NT-1 -> stores(NT-2)=4.
    cur = 0;
    stage_gl(kg, E_DIM, kbuf[0], wq, lane);
    stage_gl(vg, T_DIM, vbuf[0], wq, lane);
    for (int t = 0; t < NT; ++t) {
        if (t < NT - 1) {
            stage_gl(kg + (size_t)(t + 1) * 64 * E_DIM, E_DIM, kbuf[cur ^ 1], wq, lane);
            stage_gl(vg + (t + 1) * 64, T_DIM, vbuf[cur ^ 1], wq, lane);
        }
        if (t == 0)           BAR_VM(4);
        else if (t < NT - 1)  BAR_VM(8);   // P-stores ride 2 tiles in flight
        else                  BAR_VM(4);
        const _Float16* kb = kbuf[cur];
        const _Float16* vb = vbuf[cur];

        f32x4 acc[4];
#pragma unroll
        for (int ct = 0; ct < 4; ++ct) acc[ct] = (f32x4){0.f, 0.f, 0.f, 0.f};
#pragma unroll
        for (int ks = 0; ks < 2; ++ks)
#pragma unroll
            for (int ct = 0; ct < 4; ++ct) {
                half8 kf = read_frag64(kb, ct * 16 + l15, lg + 4 * ks);
                acc[ct] = __builtin_amdgcn_mfma_f32_16x16x32_f16(kf, qfrag[ks], acc[ct], 0, 0, 0);
            }

        // P: one plain dwordx4 global store (L2 write-combined) + b64 pbuf
        float* abrow = ab + (size_t)myq * T_DIM + t * 64 + lg * 4;
#pragma unroll
        for (int ct = 0; ct < 4; ++ct) {
            f32x4 p;
            p[0] = __builtin_amdgcn_exp2f(acc[ct][0]) * rl;
            p[1] = __builtin_amdgcn_exp2f(acc[ct][1]) * rl;
            p[2] = __builtin_amdgcn_exp2f(acc[ct][2]) * rl;
            p[3] = __builtin_amdgcn_exp2f(acc[ct][3]) * rl;
            *reinterpret_cast<f32x4*>(abrow + ct * 16) = p;
            half4v ph;
            ph[0] = (_Float16)p[0]; ph[1] = (_Float16)p[1];
            ph[2] = (_Float16)p[2]; ph[3] = (_Float16)p[3];
            int cc = (ct * 4 + lg) ^ l15;          // 4-bit XOR: bank-balanced
            *reinterpret_cast<half4v*>(pw + l15 * 64 + cc * 4) = ph;
        }

        // PV: A = P[q=l15][s], B = V[s][d] (vbuf rows are d from Vt)
#pragma unroll
        for (int ks = 0; ks < 2; ++ks) {
            int c0 = 2 * (lg + 4 * ks);
            half4v lo = *reinterpret_cast<const half4v*>(pw + l15 * 64 + ((c0)     ^ l15) * 4);
            half4v hi = *reinterpret_cast<const half4v*>(pw + l15 * 64 + ((c0 + 1) ^ l15) * 4);
            half8 pa;
            pa[0] = lo[0]; pa[1] = lo[1]; pa[2] = lo[2]; pa[3] = lo[3];
            pa[4] = hi[0]; pa[5] = hi[1]; pa[6] = hi[2]; pa[7] = hi[3];
#pragma unroll
            for (int cd = 0; cd < 4; ++cd) {
                half8 vf = read_frag64(vb, cd * 16 + l15, lg + 4 * ks);
                oacc[cd] = __builtin_amdgcn_mfma_f32_16x16x32_f16(pa, vf, oacc[cd], 0, 0, 0);
            }
        }
        bar_plain();                   // buf[cur] reads done; next overwrite ok
        cur ^= 1;
    }

    // head (f16) -> workspace [B*T][E]; O[q=lg*4+r][d=cd*16+l15]
    _Float16* hw = head_h + ((size_t)(b * T_DIM + q0 + wq * 16)) * E_DIM + h * D_HEAD;
#pragma unroll
    for (int cd = 0; cd < 4; ++cd)
#pragma unroll
        for (int r = 0; r < 4; ++r) {
            int qm = lg * 4 + r;
            hw[(size_t)qm * E_DIM + cd * 16 + l15] = (_Float16)oacc[cd][r];
        }
#undef P1TILE
}

// ---------------------------------------------------------------------------
// outputs[m][n] = sum_k head[m][k]*W[n][k]  (M=4096,N=1024,K=1024)
// Operand-swapped: acc = mfma(A=W_frag, B=head_frag) -> dwordx4 C stores.
// ---------------------------------------------------------------------------
__global__ __launch_bounds__(256) void proj_kernel(
        const _Float16* __restrict__ A, const _Float16* __restrict__ Wh,
        float* __restrict__ out) {
    __shared__ __align__(16) _Float16 abuf[2][64 * 64];
    __shared__ __align__(16) _Float16 bbuf[2][64 * 64];

    int tid  = threadIdx.x;
    int wq   = tid >> 6;
    int lane = tid & 63;
    int l15  = lane & 15;
    int lg   = lane >> 4;

    int m0 = blockIdx.x * 64;
    int n0 = blockIdx.y * 64;

    f32x4 acc[4];
#pragma unroll
    for (int ct = 0; ct < 4; ++ct) acc[ct] = (f32x4){0.f, 0.f, 0.f, 0.f};

    int cur = 0;
    stage_gl(A  + (size_t)m0 * E_DIM, E_DIM, abuf[0], wq, lane);
    stage_gl(Wh + (size_t)n0 * E_DIM, E_DIM, bbuf[0], wq, lane);
    for (int t = 0; t < E_DIM / 64; ++t) {
        if (t + 1 < E_DIM / 64) {
            stage_gl(A  + (size_t)m0 * E_DIM + (t + 1) * 64, E_DIM, abuf[cur ^ 1], wq, lane);
            stage_gl(Wh + (size_t)n0 * E_DIM + (t + 1) * 64, E_DIM, bbuf[cur ^ 1], wq, lane);
            BAR_VM(4);                 // 4 ops issued after stage(t)
        } else {
            BAR_VM(0);
        }
#pragma unroll
        for (int ks = 0; ks < 2; ++ks) {
            half8 hf = read_frag64(abuf[cur], wq * 16 + l15, lg + 4 * ks);
#pragma unroll
            for (int ct = 0; ct < 4; ++ct) {
                half8 wf = read_frag64(bbuf[cur], ct * 16 + l15, lg + 4 * ks);
                acc[ct] = __builtin_amdgcn_mfma_f32_16x16x32_f16(wf, hf, acc[ct], 0, 0, 0);
            }
        }
        bar_plain();                   // buf[cur] reads done before overwrite
        cur ^= 1;
    }

    float* orow = out + (size_t)(m0 + wq * 16 + l15) * E_DIM + n0 + lg * 4;
#pragma unroll
    for (int ct = 0; ct < 4; ++ct) {
        f32x4 o;
        o[0] = acc[ct][0]; o[1] = acc[ct][1]; o[2] = acc[ct][2]; o[3] = acc[ct][3];
        *reinterpret_cast<f32x4*>(orow + ct * 16) = o;
    }
}

// ---------------------------------------------------------------------------
extern "C" void kernel_launch(void* const* d_in, const int* in_sizes, int n_in,
                              void* d_out, int out_size, void* d_ws, size_t ws_size,
                              hipStream_t stream) {
    const float* q = (const float*)d_in[0];
    const float* k = (const float*)d_in[1];
    const float* v = (const float*)d_in[2];
    const float* w = (const float*)d_in[3];

    float* outs = (float*)d_out;
    float* attn = outs + (size_t)B_NUM * T_DIM * E_DIM;   // [32,2048,2048]

    char* ws = (char*)d_ws;
    _Float16* Kh = (_Float16*)(ws);
    _Float16* Vt = (_Float16*)(ws + (size_t)(8  << 20));
    _Float16* Wh = (_Float16*)(ws + (size_t)(16 << 20));
    _Float16* Hh = (_Float16*)(ws + (size_t)(18 << 20));

    int nqkv4 = B_NUM * T_DIM * E_DIM / 4;
    int nw4   = E_DIM * E_DIM / 4;

    cast_f16_kernel<<<1024, 256, 0, stream>>>(k, Kh, nqkv4);
    cast_f16_kernel<<<512, 256, 0, stream>>>(w, Wh, nw4);
    transpose_v_kernel<<<dim3(T_DIM / 64, BH_NUM), 256, 0, stream>>>(v, Vt);
    attn_kernel<<<NT * BH_NUM, 256, 0, stream>>>(q, Kh, Vt, attn, Hh);
    proj_kernel<<<dim3((B_NUM * T_DIM) / 64, E_DIM / 64), 256, 0, stream>>>(Hh, Wh, outs);
}